// Round 8
// baseline (235.740 us; speedup 1.0000x reference)
//
#include <hip/hip_runtime.h>
#include <hip/hip_bf16.h>

// Problem constants (match reference)
constexpr int Bq  = 4;
constexpr int Nn  = 10000;
constexpr int Eq  = 170000;
constexpr int FIN = 256;
constexpr int Ff  = 128;
constexpr int Hh  = 4;
constexpr int Mrows = Nn * Bq;  // per-head GEMM2 M = 40000 (n*4+b)
constexpr int C   = Hh * Ff;    // 512 output cols
constexpr float LEAKY = 0.2f;

typedef short short4v __attribute__((ext_vector_type(4)));
typedef short short8  __attribute__((ext_vector_type(8)));
typedef float f32x4   __attribute__((ext_vector_type(4)));

// float -> bf16 bits, round-to-nearest-even
static __device__ __forceinline__ unsigned short f2bf(float f) {
    unsigned int u = __float_as_uint(f);
    u = u + 0x7fffu + ((u >> 16) & 1u);
    return (unsigned short)(u >> 16);
}
static __device__ __forceinline__ float bf2f(unsigned short b) {
    return __uint_as_float(((unsigned int)b) << 16);
}

// ---------- K1: prep — Wf fragment layout, wa/bsd, row_start (one launch) --
__global__ __launch_bounds__(256) void prep_kernel(
    const float* __restrict__ W, const float* __restrict__ Wattn,
    const float* __restrict__ bmlp, const int* __restrict__ src,
    unsigned short* __restrict__ Wf, float* __restrict__ wa,
    float* __restrict__ bsd, int* __restrict__ row_start)
{
    int bid = blockIdx.x, t = threadIdx.x;
    if (bid < 512) {
        // Wf unit u = ((hi*8 + j)*8 + ks)*64 + quad*16 + ln holds
        // B[k = ks*32 + quad*8 + el][col = hi*128 + j*16 + ln], el = 0..7.
        int cc = bid;  // col = hi*128 + f
        int k = t;
        float v = W[(size_t)(cc >> 7) * FIN * Ff + (size_t)k * Ff + (cc & 127)];
        int w = cc >> 7, j = (cc >> 4) & 7, ln = cc & 15;
        int ks = k >> 5, quad = (k >> 3) & 3, el = k & 7;
        size_t u = ((size_t)((w * 8 + j) * 8 + ks) * 4 + quad) * 16 + ln;
        Wf[u * 8 + el] = f2bf(v);
    } else if (bid == 512) {
        // wa[v][hi][k] = sum_f W[hi][k][f]*a_v[hi][f]; bsd[v][hi] = b.a_v
        int hi = t >> 6, kb = t & 63;
        #pragma unroll
        for (int i = 0; i < 4; ++i) {
            int k = kb + i * 64;
            float ss = 0.f, sd = 0.f;
            const float* wrow = W + ((size_t)hi * FIN + k) * Ff;
            const float* as = Wattn + hi * 2 * Ff;
            const float* ad = as + Ff;
            for (int f = 0; f < Ff; f += 4) {
                float4 wv = *(const float4*)(wrow + f);
                float4 av = *(const float4*)(as + f);
                float4 dv = *(const float4*)(ad + f);
                ss += wv.x * av.x + wv.y * av.y + wv.z * av.z + wv.w * av.w;
                sd += wv.x * dv.x + wv.y * dv.y + wv.z * dv.z + wv.w * dv.w;
            }
            wa[(0 * 4 + hi) * FIN + k] = ss;
            wa[(1 * 4 + hi) * FIN + k] = sd;
        }
        if (t < 8) {
            int v = t & 1, hh = t >> 1;
            float s = 0.f;
            for (int f = 0; f < Ff; ++f)
                s += bmlp[hh * Ff + f] * Wattn[hh * 2 * Ff + v * Ff + f];
            bsd[v * 4 + hh] = s;
        }
    } else {
        int n = (bid - 513) * 256 + t;
        if (n > Nn) return;
        int lo = 0, hi = Eq;
        while (lo < hi) { int mid = (lo + hi) >> 1; if (src[mid] < n) lo = mid + 1; else hi = mid; }
        row_start[n] = lo;
    }
}

// ---------- K2: Xb[b][n][k] = bf16(x[b][n][k]) + fused projections ---------
// Same layout in and out -> pure streaming convert. b=3 slice also feeds the
// 8 attention projection dots (half-wave shuffle reduce).
__global__ __launch_bounds__(256) void xprep_proj_kernel(
    const float* __restrict__ X, const float* __restrict__ wa,
    const float* __restrict__ bsd, unsigned short* __restrict__ Xb,
    float* __restrict__ psT, float* __restrict__ pdT)
{
    int n0 = blockIdx.x * 8;
    int t  = threadIdx.x;
    int r  = t >> 5;          // 0..7 (node within block; half-wave)
    int c  = t & 31;
    int k8 = c * 8;           // 0..248
    float s[8];
    #pragma unroll
    for (int i = 0; i < 8; ++i) s[i] = 0.f;

    #pragma unroll
    for (int b = 0; b < Bq; ++b) {
        size_t lin = ((size_t)b * Nn + n0 + r) * FIN + k8;
        const float* p = X + lin;
        float4 v0 = *(const float4*)p, v1 = *(const float4*)(p + 4);
        short8 v;
        v[0] = (short)f2bf(v0.x); v[1] = (short)f2bf(v0.y);
        v[2] = (short)f2bf(v0.z); v[3] = (short)f2bf(v0.w);
        v[4] = (short)f2bf(v1.x); v[5] = (short)f2bf(v1.y);
        v[6] = (short)f2bf(v1.z); v[7] = (short)f2bf(v1.w);
        *(short8*)(Xb + lin) = v;
        if (b == Bq - 1) {
            #pragma unroll
            for (int i = 0; i < 8; ++i) {
                const float* w = wa + (size_t)i * FIN + k8;
                float4 w0 = *(const float4*)w, w1 = *(const float4*)(w + 4);
                s[i] = v0.x * w0.x + v0.y * w0.y + v0.z * w0.z + v0.w * w0.w
                     + v1.x * w1.x + v1.y * w1.y + v1.z * w1.z + v1.w * w1.w;
            }
        }
    }
    #pragma unroll
    for (int off = 1; off < 32; off <<= 1)
        #pragma unroll
        for (int i = 0; i < 8; ++i) s[i] += __shfl_xor(s[i], off, 64);
    if (c == 0) {
        int n = n0 + r;
        #pragma unroll
        for (int hi = 0; hi < 4; ++hi) {
            psT[n * 4 + hi] = s[hi]     + bsd[hi];
            pdT[n * 4 + hi] = s[4 + hi] + bsd[4 + hi];
        }
    }
}

// ---------- K3: edge scores -> PRE-NORMALIZED weights + denom --------------
__global__ __launch_bounds__(256) void edge_denom_kernel(
    const int* __restrict__ dst, const int* __restrict__ row_start,
    const float* __restrict__ psT, const float* __restrict__ pdT,
    float* __restrict__ eed, float* __restrict__ denom)
{
    int wv = threadIdx.x >> 6, t = threadIdx.x & 63;
    int n = blockIdx.x * 4 + wv;
    int e0 = row_start[n], e1 = row_start[n + 1];
    float4 ps = *(const float4*)(psT + (size_t)n * 4);
    float4 acc = {0.f, 0.f, 0.f, 0.f};
    for (int e = e0 + t; e < e1; e += 64) {
        int d = dst[e];
        float4 pd = *(const float4*)(pdT + (size_t)d * 4);
        float4 ev;
        { float sc = ps.x + pd.x; float lr = sc > 0.f ? sc : LEAKY * sc;
          ev.x = __expf(fminf(fmaxf(lr, -2.f), 2.f)); }
        { float sc = ps.y + pd.y; float lr = sc > 0.f ? sc : LEAKY * sc;
          ev.y = __expf(fminf(fmaxf(lr, -2.f), 2.f)); }
        { float sc = ps.z + pd.z; float lr = sc > 0.f ? sc : LEAKY * sc;
          ev.z = __expf(fminf(fmaxf(lr, -2.f), 2.f)); }
        { float sc = ps.w + pd.w; float lr = sc > 0.f ? sc : LEAKY * sc;
          ev.w = __expf(fminf(fmaxf(lr, -2.f), 2.f)); }
        *(float4*)(eed + (size_t)e * 4) = ev;
        acc.x += ev.x; acc.y += ev.y; acc.z += ev.z; acc.w += ev.w;
    }
    #pragma unroll
    for (int off = 1; off < 64; off <<= 1) {
        acc.x += __shfl_xor(acc.x, off, 64);
        acc.y += __shfl_xor(acc.y, off, 64);
        acc.z += __shfl_xor(acc.z, off, 64);
        acc.w += __shfl_xor(acc.w, off, 64);
    }
    if (t == 0) *(float4*)(denom + (size_t)n * 4) = acc;
    float4 inv;
    inv.x = acc.x != 0.f ? 1.f / acc.x : 0.f;
    inv.y = acc.y != 0.f ? 1.f / acc.y : 0.f;
    inv.z = acc.z != 0.f ? 1.f / acc.z : 0.f;
    inv.w = acc.w != 0.f ? 1.f / acc.w : 0.f;
    for (int e = e0 + t; e < e1; e += 64) {
        float4 ev = *(const float4*)(eed + (size_t)e * 4);
        ev.x *= inv.x; ev.y *= inv.y; ev.z *= inv.z; ev.w *= inv.w;
        *(float4*)(eed + (size_t)e * 4) = ev;
    }
}

// ---------- K4: gather, batch-split for L2 phase locality ------------------
// grid (Nn/4, Bq), blockIdx.x fastest => all batch-0 blocks dispatch first;
// per-phase working set = 5.12 MB (vs 4 MB L2/XCD). Wave handles one (n,b):
// per edge one 512B coalesced read, 4-edge unroll, acc[hi][4] per lane.
__global__ __launch_bounds__(256) void gather_kernel(
    const unsigned short* __restrict__ Xb, const float* __restrict__ eed,
    const int* __restrict__ row_start, const int* __restrict__ dst,
    unsigned short* __restrict__ Gx)
{
    int wv = threadIdx.x >> 6, t = threadIdx.x & 63;
    int n = blockIdx.x * 4 + wv;
    int b = blockIdx.y;
    int e0 = row_start[n], e1 = row_start[n + 1];
    const unsigned short* Xbb = Xb + (size_t)b * Nn * FIN;
    int off = t * 4;

    float acc[4][4];
    #pragma unroll
    for (int hi = 0; hi < 4; ++hi)
        #pragma unroll
        for (int j = 0; j < 4; ++j) acc[hi][j] = 0.f;

    const float4* eed4 = (const float4*)eed;
    int e = e0;
    for (; e + 4 <= e1; e += 4) {
        int d0 = dst[e], d1 = dst[e + 1], d2 = dst[e + 2], d3 = dst[e + 3];
        short4v v0 = *(const short4v*)(Xbb + (size_t)d0 * FIN + off);
        short4v v1 = *(const short4v*)(Xbb + (size_t)d1 * FIN + off);
        short4v v2 = *(const short4v*)(Xbb + (size_t)d2 * FIN + off);
        short4v v3 = *(const short4v*)(Xbb + (size_t)d3 * FIN + off);
        float4 ev0 = eed4[e], ev1 = eed4[e + 1], ev2 = eed4[e + 2], ev3 = eed4[e + 3];
        #pragma unroll
        for (int j = 0; j < 4; ++j) {
            float f0 = bf2f((unsigned short)v0[j]);
            float f1 = bf2f((unsigned short)v1[j]);
            float f2 = bf2f((unsigned short)v2[j]);
            float f3 = bf2f((unsigned short)v3[j]);
            acc[0][j] += f0 * ev0.x + f1 * ev1.x + f2 * ev2.x + f3 * ev3.x;
            acc[1][j] += f0 * ev0.y + f1 * ev1.y + f2 * ev2.y + f3 * ev3.y;
            acc[2][j] += f0 * ev0.z + f1 * ev1.z + f2 * ev2.z + f3 * ev3.z;
            acc[3][j] += f0 * ev0.w + f1 * ev1.w + f2 * ev2.w + f3 * ev3.w;
        }
    }
    for (; e < e1; ++e) {
        int d0 = dst[e];
        short4v v0 = *(const short4v*)(Xbb + (size_t)d0 * FIN + off);
        float4 ev0 = eed4[e];
        #pragma unroll
        for (int j = 0; j < 4; ++j) {
            float f = bf2f((unsigned short)v0[j]);
            acc[0][j] += f * ev0.x; acc[1][j] += f * ev0.y;
            acc[2][j] += f * ev0.z; acc[3][j] += f * ev0.w;
        }
    }

    #pragma unroll
    for (int hi = 0; hi < 4; ++hi) {
        short4v o;
        #pragma unroll
        for (int j = 0; j < 4; ++j) o[j] = (short)f2bf(acc[hi][j]);
        *(short4v*)(Gx + ((size_t)hi * Mrows + (size_t)n * 4 + b) * FIN + off) = o;
    }
}

// ---------- K5: out = Gx @ W[hi] + bias*(denom!=0), per head, 64-row -------
// grid (625, 4). Wave w -> rows [w*16, w*16+16). LDS-repacked epilogue for
// contiguous 512B float4 row stores.
__global__ __launch_bounds__(256) void gemm2_kernel(
    const unsigned short* __restrict__ Gx, const unsigned short* __restrict__ Wf,
    const float* __restrict__ bias, const float* __restrict__ denom,
    float* __restrict__ out)
{
    __shared__ unsigned short As[64][264]; // 33.8 KB; reused as float[64][132]

    const int hi = blockIdx.y;
    const int r0 = blockIdx.x * 64;
    const int tid = threadIdx.x;
    const int wave = tid >> 6, lane = tid & 63;
    const int quad = lane >> 4, ln = lane & 15;

    const unsigned short* Arows = Gx + ((size_t)hi * Mrows + r0) * FIN;
    #pragma unroll
    for (int i = 0; i < 8; ++i) {
        int u = tid + i * 256;      // 2048 units of 8 shorts
        int row = u >> 5, cu = u & 31;
        *(short8*)&As[row][cu * 8] = *(const short8*)(Arows + (size_t)row * FIN + cu * 8);
    }
    __syncthreads();

    f32x4 macc[8];
    #pragma unroll
    for (int j = 0; j < 8; ++j) macc[j] = (f32x4){0.f, 0.f, 0.f, 0.f};

    const short8* Wf8 = (const short8*)Wf;
    const int m0 = wave * 16;
    #pragma unroll
    for (int ks = 0; ks < 8; ++ks) {
        short8 a = *(const short8*)&As[m0 + ln][ks * 32 + quad * 8];
        #pragma unroll
        for (int j = 0; j < 8; ++j) {
            short8 bf = Wf8[(size_t)((hi * 8 + j) * 8 + ks) * 64 + lane];
            macc[j] = __builtin_amdgcn_mfma_f32_16x16x32_bf16(a, bf, macc[j], 0, 0, 0);
        }
    }
    __syncthreads();

    // repack: Lf[m][colf] = acc + bias*flag  (stride 132 floats = As row bytes)
    float* Lf = (float*)As;
    #pragma unroll
    for (int j = 0; j < 8; ++j) {
        int colf = j * 16 + ln;     // col within head, 0..127
        float bv = bias[hi * Ff + colf];
        #pragma unroll
        for (int r = 0; r < 4; ++r) {
            int m = m0 + quad * 4 + r;
            int nn = (r0 + m) >> 2;
            float flag = denom[(size_t)nn * 4 + hi] != 0.f ? 1.f : 0.f;
            Lf[m * 132 + colf] = macc[j][r] + bv * flag;
        }
    }
    __syncthreads();

    // cooperative contiguous stores: 64 rows x 32 float4 units
    #pragma unroll
    for (int i = 0; i < 8; ++i) {
        int u = tid + i * 256;
        int row = u >> 5, cu = u & 31;
        int g = r0 + row;
        int nn = g >> 2, bb = g & 3;
        float4 v = *(const float4*)&Lf[row * 132 + cu * 4];
        *(float4*)(out + ((size_t)bb * Nn + nn) * C + hi * Ff + cu * 4) = v;
    }
}

// -------------------- launch --------------------
extern "C" void kernel_launch(void* const* d_in, const int* in_sizes, int n_in,
                              void* d_out, int out_size, void* d_ws, size_t ws_size,
                              hipStream_t stream)
{
    const float* x      = (const float*)d_in[0]; // (B,N,256)
    const float* W_mlp  = (const float*)d_in[1]; // (H,256,128)
    const float* b_mlp  = (const float*)d_in[2]; // (H,128)
    const float* W_attn = (const float*)d_in[3]; // (H,256,1)
    const int*   src    = (const int*)d_in[4];   // (E,)
    const int*   dst    = (const int*)d_in[5];   // (E,)
    float* out = (float*)d_out;                  // (B,N,512)

    // workspace layout
    unsigned short* Xb  = (unsigned short*)d_ws;          // (b,n,k) bf16 = 20.48 MB
    unsigned short* Wf  = Xb + (size_t)Bq * Nn * FIN;     // 512*256 bf16
    unsigned short* Gx  = Wf + (size_t)C * FIN;           // 4*40000*256 bf16 = 81.92 MB
    float* eed   = (float*)(Gx + (size_t)Hh * Mrows * FIN); // E*4 floats
    float* psT   = eed + (size_t)Eq * 4;                  // N*4
    float* pdT   = psT + (size_t)Nn * 4;                  // N*4
    float* denom = pdT + (size_t)Nn * 4;                  // N*4
    float* wa    = denom + (size_t)Nn * 4;                // 2*4*256
    float* bsd   = wa + 2 * 4 * FIN;                      // 8 (pad 16)
    int*   row_st = (int*)(bsd + 16);                     // N+1

    hipLaunchKernelGGL(prep_kernel, dim3(553), dim3(256), 0, stream,
                       W_mlp, W_attn, b_mlp, src, Wf, wa, bsd, row_st);
    hipLaunchKernelGGL(xprep_proj_kernel, dim3(Nn / 8), dim3(256), 0, stream,
                       x, wa, bsd, Xb, psT, pdT);
    hipLaunchKernelGGL(edge_denom_kernel, dim3(Nn / 4), dim3(256), 0, stream,
                       dst, row_st, psT, pdT, eed, denom);
    hipLaunchKernelGGL(gather_kernel, dim3(Nn / 4, Bq), dim3(256), 0, stream,
                       Xb, eed, row_st, dst, Gx);
    hipLaunchKernelGGL(gemm2_kernel, dim3(Mrows / 64, Hh), dim3(256), 0, stream,
                       Gx, Wf, b_mlp, denom, out);
}